// Round 1
// baseline (98.181 us; speedup 1.0000x reference)
//
#include <hip/hip_runtime.h>

// Problem geometry (fixed by reference):
//   SHAPE = (16, 128, 4096, 3); rows = 16*128 = 2048; row_len = 4096*3 = 12288
//   NUM_CLASSES = 128, L2_LAMBDA = 0.01, S2 = 2.0
#define ROWS     2048
#define ROW_LEN  12288
#define ROW_VEC  3072          // float4s per row
#define NT       256

// Kernel 1: one block per (batch,point) row.
// Computes per-row:  so = sum (out-t)^2, s1 = sum (gt1-t)^2, s2 = sum (gt2m-t)^2,
//                    sb = sum (-log(v) + v*v/8)      over the 12288-elem row,
// then writes float4 { sqrt(so), sqrt(s1), sqrt(s2), kl_part } to rowbuf[row],
// where kl_part = 1.4*(sb + 12288*(ln2 - 0.5)) + 0.125*(so + 0.2*s1 + 0.2*s2).
__global__ __launch_bounds__(NT) void row_reduce_kernel(
    const float* __restrict__ outp,
    const float* __restrict__ targp,
    const float* __restrict__ g1p,
    const float* __restrict__ g2p,
    const float* __restrict__ gvp,
    float4* __restrict__ rowbuf)
{
    const size_t base = (size_t)blockIdx.x * ROW_LEN;
    const float4* __restrict__ o4 = (const float4*)(outp + base);
    const float4* __restrict__ t4 = (const float4*)(targp + base);
    const float4* __restrict__ a4 = (const float4*)(g1p + base);
    const float4* __restrict__ b4 = (const float4*)(g2p + base);
    const float4* __restrict__ v4 = (const float4*)(gvp + base);

    float so = 0.f, s1 = 0.f, s2 = 0.f, sb = 0.f;

    #pragma unroll 4
    for (int i = threadIdx.x; i < ROW_VEC; i += NT) {
        const float4 t = t4[i];
        const float4 o = o4[i];
        const float4 a = a4[i];
        const float4 b = b4[i];
        const float4 v = v4[i];
        float d;
        d = o.x - t.x; so = fmaf(d, d, so);
        d = o.y - t.y; so = fmaf(d, d, so);
        d = o.z - t.z; so = fmaf(d, d, so);
        d = o.w - t.w; so = fmaf(d, d, so);

        d = a.x - t.x; s1 = fmaf(d, d, s1);
        d = a.y - t.y; s1 = fmaf(d, d, s1);
        d = a.z - t.z; s1 = fmaf(d, d, s1);
        d = a.w - t.w; s1 = fmaf(d, d, s1);

        d = b.x - t.x; s2 = fmaf(d, d, s2);
        d = b.y - t.y; s2 = fmaf(d, d, s2);
        d = b.z - t.z; s2 = fmaf(d, d, s2);
        d = b.w - t.w; s2 = fmaf(d, d, s2);

        sb += fmaf(v.x, v.x * 0.125f, -__logf(v.x));
        sb += fmaf(v.y, v.y * 0.125f, -__logf(v.y));
        sb += fmaf(v.z, v.z * 0.125f, -__logf(v.z));
        sb += fmaf(v.w, v.w * 0.125f, -__logf(v.w));
    }

    // wave-64 butterfly reduce
    #pragma unroll
    for (int off = 32; off > 0; off >>= 1) {
        so += __shfl_down(so, off);
        s1 += __shfl_down(s1, off);
        s2 += __shfl_down(s2, off);
        sb += __shfl_down(sb, off);
    }

    __shared__ float red[4][4];   // [wave][value]
    const int wid  = threadIdx.x >> 6;
    const int lane = threadIdx.x & 63;
    if (lane == 0) {
        red[wid][0] = so; red[wid][1] = s1; red[wid][2] = s2; red[wid][3] = sb;
    }
    __syncthreads();
    if (threadIdx.x == 0) {
        float r0 = 0.f, r1 = 0.f, r2 = 0.f, r3 = 0.f;
        #pragma unroll
        for (int w = 0; w < 4; ++w) {
            r0 += red[w][0]; r1 += red[w][1]; r2 += red[w][2]; r3 += red[w][3];
        }
        // per-element constant part of base: (ln2 - 0.5) per element, 12288 elems
        const float const_base = 12288.f * (0.69314718056f - 0.5f);
        const float kl_part = 1.4f * (r3 + const_base)
                            + 0.125f * (r0 + 0.2f * r1 + 0.2f * r2);
        float4 r;
        r.x = sqrtf(r0);
        r.y = sqrtf(r1);
        r.z = sqrtf(r2);
        r.w = kl_part;
        rowbuf[blockIdx.x] = r;
    }
}

// Kernel 2: single block; deterministic reduction of the 2048 row records +
// final scalar formula.
__global__ __launch_bounds__(256) void final_kernel(
    const float4* __restrict__ rowbuf,
    const float* __restrict__ gt0p,
    const float* __restrict__ legp,
    const float* __restrict__ ldynp,
    float* __restrict__ resp)
{
    float a0 = 0.f, a1 = 0.f, a2 = 0.f, a3 = 0.f;
    for (int i = threadIdx.x; i < ROWS; i += 256) {
        const float4 r = rowbuf[i];
        a0 += r.x; a1 += r.y; a2 += r.z; a3 += r.w;
    }
    #pragma unroll
    for (int off = 32; off > 0; off >>= 1) {
        a0 += __shfl_down(a0, off);
        a1 += __shfl_down(a1, off);
        a2 += __shfl_down(a2, off);
        a3 += __shfl_down(a3, off);
    }
    __shared__ float red[4][4];
    const int wid  = threadIdx.x >> 6;
    const int lane = threadIdx.x & 63;
    if (lane == 0) {
        red[wid][0] = a0; red[wid][1] = a1; red[wid][2] = a2; red[wid][3] = a3;
    }
    __syncthreads();
    if (threadIdx.x == 0) {
        float r0 = 0.f, r1 = 0.f, r2 = 0.f, r3 = 0.f;
        #pragma unroll
        for (int w = 0; w < 4; ++w) {
            r0 += red[w][0]; r1 += red[w][1]; r2 += red[w][2]; r3 += red[w][3];
        }
        const float Eo = r0 * (1.f / 128.f);   // euc(out)
        const float E1 = r1 * (1.f / 128.f);   // euc(gt1_mean)
        const float E2 = r2 * (1.f / 128.f);   // euc(gt2_mean)
        const float kl = r3;

        const float l_dyn = ldynp[0];
        const float leg_term = 0.01f * 0.2f * l_dyn * legp[0];
        const float outloss  = Eo + leg_term;
        const float gt_loss  = 0.1f * E1 + 0.2f * E2;
        const float reg      = gt0p[0] * 0.01f * l_dyn;

        resp[0] = outloss + gt_loss + reg + kl / (1.2f * (Eo + gt_loss));
    }
}

extern "C" void kernel_launch(void* const* d_in, const int* in_sizes, int n_in,
                              void* d_out, int out_size, void* d_ws, size_t ws_size,
                              hipStream_t stream) {
    // setup_inputs() order:
    //   0: out        [16,128,4096,3] f32
    //   1: target     [16,128,4096,3] f32
    //   2: gt0        scalar f32
    //   3: gt1_mean   [16,128,4096,3] f32
    //   4: gt2_mean   [16,128,4096,3] f32
    //   5: gt2_var    [16,128,4096,3] f32
    //   6: leg        scalar f32
    //   7: l_dynamic  scalar f32
    const float* outp  = (const float*)d_in[0];
    const float* targp = (const float*)d_in[1];
    const float* gt0p  = (const float*)d_in[2];
    const float* g1p   = (const float*)d_in[3];
    const float* g2p   = (const float*)d_in[4];
    const float* gvp   = (const float*)d_in[5];
    const float* legp  = (const float*)d_in[6];
    const float* ldynp = (const float*)d_in[7];

    float4* rowbuf = (float4*)d_ws;          // 2048 * 16 B = 32 KiB
    float*  resp   = (float*)d_out;

    row_reduce_kernel<<<ROWS, NT, 0, stream>>>(outp, targp, g1p, g2p, gvp, rowbuf);
    final_kernel<<<1, 256, 0, stream>>>(rowbuf, gt0p, legp, ldynp, resp);
}

// Round 2
// 94.069 us; speedup vs baseline: 1.0437x; 1.0437x over previous
//
#include <hip/hip_runtime.h>

// SHAPE = (16, 128, 4096, 3): rows = 2048, row_len = 12288 floats = 3072 float4
// Total elements per array = 25,165,824.
// pass1 grid = 4096 blocks:
//   blocks 0..2047    : per-row euclid sums over {out, gt1, gt2} vs target (4 streams)
//   blocks 2048..4095 : gt2_var partial sums of (-log v + v^2/8)   (1 stream)
#define NROW    2048
#define ROW_V4  3072
#define NT      256
#define ITERS   12            // ROW_V4 / NT

__global__ __launch_bounds__(NT) void pass1(
    const float* __restrict__ outp,
    const float* __restrict__ targp,
    const float* __restrict__ g1p,
    const float* __restrict__ g2p,
    const float* __restrict__ gvp,
    float4* __restrict__ rowbuf,     // [2048] {sqrt(so), sqrt(s1), sqrt(s2), sq-combo}
    float*  __restrict__ varbuf)     // [2048] partial sums of (-log v + v^2/8)
{
    __shared__ float red[4][3];
    const int bid  = blockIdx.x;
    const int tid  = threadIdx.x;
    const int wid  = tid >> 6;
    const int lane = tid & 63;

    if (bid < NROW) {
        const size_t base = (size_t)bid * ROW_V4;
        const float4* __restrict__ t4 = (const float4*)targp + base;
        const float4* __restrict__ o4 = (const float4*)outp  + base;
        const float4* __restrict__ a4 = (const float4*)g1p   + base;
        const float4* __restrict__ b4 = (const float4*)g2p   + base;

        float so = 0.f, s1 = 0.f, s2 = 0.f;
        #pragma unroll 2
        for (int ii = 0; ii < ITERS; ++ii) {
            const int i = tid + ii * NT;
            const float4 t = t4[i];
            const float4 o = o4[i];
            const float4 a = a4[i];
            const float4 b = b4[i];
            float d;
            d = o.x - t.x; so = fmaf(d, d, so);
            d = o.y - t.y; so = fmaf(d, d, so);
            d = o.z - t.z; so = fmaf(d, d, so);
            d = o.w - t.w; so = fmaf(d, d, so);
            d = a.x - t.x; s1 = fmaf(d, d, s1);
            d = a.y - t.y; s1 = fmaf(d, d, s1);
            d = a.z - t.z; s1 = fmaf(d, d, s1);
            d = a.w - t.w; s1 = fmaf(d, d, s1);
            d = b.x - t.x; s2 = fmaf(d, d, s2);
            d = b.y - t.y; s2 = fmaf(d, d, s2);
            d = b.z - t.z; s2 = fmaf(d, d, s2);
            d = b.w - t.w; s2 = fmaf(d, d, s2);
        }
        #pragma unroll
        for (int off = 32; off; off >>= 1) {
            so += __shfl_down(so, off);
            s1 += __shfl_down(s1, off);
            s2 += __shfl_down(s2, off);
        }
        if (lane == 0) { red[wid][0] = so; red[wid][1] = s1; red[wid][2] = s2; }
        __syncthreads();
        if (tid == 0) {
            float r0 = 0.f, r1 = 0.f, r2 = 0.f;
            #pragma unroll
            for (int w = 0; w < 4; ++w) { r0 += red[w][0]; r1 += red[w][1]; r2 += red[w][2]; }
            float4 r;
            r.x = sqrtf(r0);
            r.y = sqrtf(r1);
            r.z = sqrtf(r2);
            r.w = fmaf(0.125f, r0, fmaf(0.025f, r1, 0.025f * r2));  // KL sq-diff combo
            rowbuf[bid] = r;
        }
    } else {
        const size_t base = (size_t)(bid - NROW) * ROW_V4;
        const float4* __restrict__ v4 = (const float4*)gvp + base;
        float sb = 0.f;
        #pragma unroll 4
        for (int ii = 0; ii < ITERS; ++ii) {
            const float4 v = v4[tid + ii * NT];
            sb += fmaf(v.x, v.x * 0.125f, -__logf(v.x));
            sb += fmaf(v.y, v.y * 0.125f, -__logf(v.y));
            sb += fmaf(v.z, v.z * 0.125f, -__logf(v.z));
            sb += fmaf(v.w, v.w * 0.125f, -__logf(v.w));
        }
        #pragma unroll
        for (int off = 32; off; off >>= 1) sb += __shfl_down(sb, off);
        if (lane == 0) red[wid][0] = sb;
        __syncthreads();
        if (tid == 0)
            varbuf[bid - NROW] = red[0][0] + red[1][0] + red[2][0] + red[3][0];
    }
}

// Deterministic final reduction + scalar formula (single block).
__global__ __launch_bounds__(256) void final_kernel(
    const float4* __restrict__ rowbuf,
    const float*  __restrict__ varbuf,
    const float*  __restrict__ gt0p,
    const float*  __restrict__ legp,
    const float*  __restrict__ ldynp,
    float* __restrict__ resp)
{
    float a0 = 0.f, a1 = 0.f, a2 = 0.f, a3 = 0.f, sb = 0.f;
    for (int i = threadIdx.x; i < NROW; i += 256) {
        const float4 r = rowbuf[i];
        a0 += r.x; a1 += r.y; a2 += r.z; a3 += r.w;
        sb += varbuf[i];
    }
    #pragma unroll
    for (int off = 32; off; off >>= 1) {
        a0 += __shfl_down(a0, off);
        a1 += __shfl_down(a1, off);
        a2 += __shfl_down(a2, off);
        a3 += __shfl_down(a3, off);
        sb += __shfl_down(sb, off);
    }
    __shared__ float red[4][5];
    const int wid  = threadIdx.x >> 6;
    const int lane = threadIdx.x & 63;
    if (lane == 0) {
        red[wid][0] = a0; red[wid][1] = a1; red[wid][2] = a2;
        red[wid][3] = a3; red[wid][4] = sb;
    }
    __syncthreads();
    if (threadIdx.x == 0) {
        float r0 = 0.f, r1 = 0.f, r2 = 0.f, r3 = 0.f, rb = 0.f;
        #pragma unroll
        for (int w = 0; w < 4; ++w) {
            r0 += red[w][0]; r1 += red[w][1]; r2 += red[w][2];
            r3 += red[w][3]; rb += red[w][4];
        }
        const float Eo = r0 * (1.f / 128.f);
        const float E1 = r1 * (1.f / 128.f);
        const float E2 = r2 * (1.f / 128.f);
        // kl = 1.4*(SB + N*(ln2 - 0.5)) + (SO + 0.2*S1 + 0.2*S2)/8
        const float kl = 1.4f * (rb + 25165824.f * (0.69314718056f - 0.5f)) + r3;

        const float l_dyn    = ldynp[0];
        const float leg_term = 0.01f * 0.2f * l_dyn * legp[0];
        const float outloss  = Eo + leg_term;
        const float gt_loss  = 0.1f * E1 + 0.2f * E2;
        const float reg      = gt0p[0] * 0.01f * l_dyn;

        resp[0] = outloss + gt_loss + reg + kl / (1.2f * (Eo + gt_loss));
    }
}

extern "C" void kernel_launch(void* const* d_in, const int* in_sizes, int n_in,
                              void* d_out, int out_size, void* d_ws, size_t ws_size,
                              hipStream_t stream) {
    const float* outp  = (const float*)d_in[0];
    const float* targp = (const float*)d_in[1];
    const float* gt0p  = (const float*)d_in[2];
    const float* g1p   = (const float*)d_in[3];
    const float* g2p   = (const float*)d_in[4];
    const float* gvp   = (const float*)d_in[5];
    const float* legp  = (const float*)d_in[6];
    const float* ldynp = (const float*)d_in[7];

    float4* rowbuf = (float4*)d_ws;                 // 2048 * 16 B
    float*  varbuf = (float*)(rowbuf + NROW);       // 2048 * 4 B
    float*  resp   = (float*)d_out;

    pass1<<<2 * NROW, NT, 0, stream>>>(outp, targp, g1p, g2p, gvp, rowbuf, varbuf);
    final_kernel<<<1, 256, 0, stream>>>(rowbuf, varbuf, gt0p, legp, ldynp, resp);
}

// Round 3
// 93.199 us; speedup vs baseline: 1.0535x; 1.0093x over previous
//
#include <hip/hip_runtime.h>

// SHAPE = (16, 128, 4096, 3): rows = 2048, row_len = 12288 floats = 3072 float4
// pass1 grid = 4096 blocks:
//   blocks 0..2047    : per-row euclid sums over {out, gt1, gt2} vs target (4 streams)
//   blocks 2048..4095 : gt2_var partial sums of (-log v + v^2/8)   (1 stream)
// Deep explicit load batches (16 float4 in flight on the euclid path) to raise
// per-wave memory-level parallelism past the compiler's register-minimizing
// schedule (R2: VGPR=32 -> ~2 loads in flight -> latency-bound at 22% HBM).
#define NROW    2048
#define ROW_V4  3072
#define NT      256

__global__ __launch_bounds__(NT) void pass1(
    const float* __restrict__ outp,
    const float* __restrict__ targp,
    const float* __restrict__ g1p,
    const float* __restrict__ g2p,
    const float* __restrict__ gvp,
    float4* __restrict__ rowbuf,     // [2048] {sqrt(so), sqrt(s1), sqrt(s2), sq-combo}
    float*  __restrict__ varbuf)     // [2048] partial sums of (-log v + v^2/8)
{
    __shared__ float red[4][3];
    const int bid  = blockIdx.x;
    const int tid  = threadIdx.x;
    const int wid  = tid >> 6;
    const int lane = tid & 63;

    if (bid < NROW) {
        const size_t base = (size_t)bid * ROW_V4;
        const float4* __restrict__ t4 = (const float4*)targp + base;
        const float4* __restrict__ o4 = (const float4*)outp  + base;
        const float4* __restrict__ a4 = (const float4*)g1p   + base;
        const float4* __restrict__ b4 = (const float4*)g2p   + base;

        float so = 0.f, s1 = 0.f, s2 = 0.f;
        // 12 iterations = 3 groups x 4; each group issues 16 independent loads.
        #pragma unroll
        for (int g = 0; g < 3; ++g) {
            const int i0 = tid + g * (4 * NT);
            float4 T[4], O[4], A[4], B[4];
            #pragma unroll
            for (int j = 0; j < 4; ++j) T[j] = t4[i0 + j * NT];
            #pragma unroll
            for (int j = 0; j < 4; ++j) O[j] = o4[i0 + j * NT];
            #pragma unroll
            for (int j = 0; j < 4; ++j) A[j] = a4[i0 + j * NT];
            #pragma unroll
            for (int j = 0; j < 4; ++j) B[j] = b4[i0 + j * NT];
            #pragma unroll
            for (int j = 0; j < 4; ++j) {
                float d;
                d = O[j].x - T[j].x; so = fmaf(d, d, so);
                d = O[j].y - T[j].y; so = fmaf(d, d, so);
                d = O[j].z - T[j].z; so = fmaf(d, d, so);
                d = O[j].w - T[j].w; so = fmaf(d, d, so);
                d = A[j].x - T[j].x; s1 = fmaf(d, d, s1);
                d = A[j].y - T[j].y; s1 = fmaf(d, d, s1);
                d = A[j].z - T[j].z; s1 = fmaf(d, d, s1);
                d = A[j].w - T[j].w; s1 = fmaf(d, d, s1);
                d = B[j].x - T[j].x; s2 = fmaf(d, d, s2);
                d = B[j].y - T[j].y; s2 = fmaf(d, d, s2);
                d = B[j].z - T[j].z; s2 = fmaf(d, d, s2);
                d = B[j].w - T[j].w; s2 = fmaf(d, d, s2);
            }
        }
        #pragma unroll
        for (int off = 32; off; off >>= 1) {
            so += __shfl_down(so, off);
            s1 += __shfl_down(s1, off);
            s2 += __shfl_down(s2, off);
        }
        if (lane == 0) { red[wid][0] = so; red[wid][1] = s1; red[wid][2] = s2; }
        __syncthreads();
        if (tid == 0) {
            float r0 = 0.f, r1 = 0.f, r2 = 0.f;
            #pragma unroll
            for (int w = 0; w < 4; ++w) { r0 += red[w][0]; r1 += red[w][1]; r2 += red[w][2]; }
            float4 r;
            r.x = sqrtf(r0);
            r.y = sqrtf(r1);
            r.z = sqrtf(r2);
            r.w = fmaf(0.125f, r0, fmaf(0.025f, r1, 0.025f * r2));  // KL sq-diff combo
            rowbuf[bid] = r;
        }
    } else {
        const size_t base = (size_t)(bid - NROW) * ROW_V4;
        const float4* __restrict__ v4 = (const float4*)gvp + base;
        float sb = 0.f;
        // 12 iterations = 2 groups x 6; each group issues 6 independent loads.
        #pragma unroll
        for (int g = 0; g < 2; ++g) {
            const int i0 = tid + g * (6 * NT);
            float4 V[6];
            #pragma unroll
            for (int j = 0; j < 6; ++j) V[j] = v4[i0 + j * NT];
            #pragma unroll
            for (int j = 0; j < 6; ++j) {
                sb += fmaf(V[j].x, V[j].x * 0.125f, -__logf(V[j].x));
                sb += fmaf(V[j].y, V[j].y * 0.125f, -__logf(V[j].y));
                sb += fmaf(V[j].z, V[j].z * 0.125f, -__logf(V[j].z));
                sb += fmaf(V[j].w, V[j].w * 0.125f, -__logf(V[j].w));
            }
        }
        #pragma unroll
        for (int off = 32; off; off >>= 1) sb += __shfl_down(sb, off);
        if (lane == 0) red[wid][0] = sb;
        __syncthreads();
        if (tid == 0)
            varbuf[bid - NROW] = red[0][0] + red[1][0] + red[2][0] + red[3][0];
    }
}

// Deterministic final reduction + scalar formula (single block).
__global__ __launch_bounds__(256) void final_kernel(
    const float4* __restrict__ rowbuf,
    const float*  __restrict__ varbuf,
    const float*  __restrict__ gt0p,
    const float*  __restrict__ legp,
    const float*  __restrict__ ldynp,
    float* __restrict__ resp)
{
    float a0 = 0.f, a1 = 0.f, a2 = 0.f, a3 = 0.f, sb = 0.f;
    for (int i = threadIdx.x; i < NROW; i += 256) {
        const float4 r = rowbuf[i];
        a0 += r.x; a1 += r.y; a2 += r.z; a3 += r.w;
        sb += varbuf[i];
    }
    #pragma unroll
    for (int off = 32; off; off >>= 1) {
        a0 += __shfl_down(a0, off);
        a1 += __shfl_down(a1, off);
        a2 += __shfl_down(a2, off);
        a3 += __shfl_down(a3, off);
        sb += __shfl_down(sb, off);
    }
    __shared__ float red[4][5];
    const int wid  = threadIdx.x >> 6;
    const int lane = threadIdx.x & 63;
    if (lane == 0) {
        red[wid][0] = a0; red[wid][1] = a1; red[wid][2] = a2;
        red[wid][3] = a3; red[wid][4] = sb;
    }
    __syncthreads();
    if (threadIdx.x == 0) {
        float r0 = 0.f, r1 = 0.f, r2 = 0.f, r3 = 0.f, rb = 0.f;
        #pragma unroll
        for (int w = 0; w < 4; ++w) {
            r0 += red[w][0]; r1 += red[w][1]; r2 += red[w][2];
            r3 += red[w][3]; rb += red[w][4];
        }
        const float Eo = r0 * (1.f / 128.f);
        const float E1 = r1 * (1.f / 128.f);
        const float E2 = r2 * (1.f / 128.f);
        // kl = 1.4*(SB + N*(ln2 - 0.5)) + (SO + 0.2*S1 + 0.2*S2)/8
        const float kl = 1.4f * (rb + 25165824.f * (0.69314718056f - 0.5f)) + r3;

        const float l_dyn    = ldynp[0];
        const float leg_term = 0.01f * 0.2f * l_dyn * legp[0];
        const float outloss  = Eo + leg_term;
        const float gt_loss  = 0.1f * E1 + 0.2f * E2;
        const float reg      = gt0p[0] * 0.01f * l_dyn;

        resp[0] = outloss + gt_loss + reg + kl / (1.2f * (Eo + gt_loss));
    }
}

extern "C" void kernel_launch(void* const* d_in, const int* in_sizes, int n_in,
                              void* d_out, int out_size, void* d_ws, size_t ws_size,
                              hipStream_t stream) {
    const float* outp  = (const float*)d_in[0];
    const float* targp = (const float*)d_in[1];
    const float* gt0p  = (const float*)d_in[2];
    const float* g1p   = (const float*)d_in[3];
    const float* g2p   = (const float*)d_in[4];
    const float* gvp   = (const float*)d_in[5];
    const float* legp  = (const float*)d_in[6];
    const float* ldynp = (const float*)d_in[7];

    float4* rowbuf = (float4*)d_ws;                 // 2048 * 16 B
    float*  varbuf = (float*)(rowbuf + NROW);       // 2048 * 4 B
    float*  resp   = (float*)d_out;

    pass1<<<2 * NROW, NT, 0, stream>>>(outp, targp, g1p, g2p, gvp, rowbuf, varbuf);
    final_kernel<<<1, 256, 0, stream>>>(rowbuf, varbuf, gt0p, legp, ldynp, resp);
}